// Round 1
// baseline (4604.998 us; speedup 1.0000x reference)
//
#include <hip/hip_runtime.h>
#include <cstdio>
#include <cstdint>

#define B_   128
#define L_   512
#define H_   512
#define IN_  64
#define OUT_ 64
#define NH_  8
#define HD_  64
#define HOR_ 24
#define KCAT 576   // IN_ + H_
#define G4H  2048  // 4*H_

typedef unsigned short u16;
typedef __attribute__((ext_vector_type(8))) __bf16 bf16x8;
typedef __attribute__((ext_vector_type(4))) float f32x4;

__device__ __forceinline__ float bfbits2f(uint32_t hi){ union { uint32_t u; float f; } v; v.u = hi; return v.f; }
__device__ __forceinline__ float bf2f(u16 u){ union { uint32_t u; float f; } v; v.u = ((uint32_t)u) << 16; return v.f; }
__device__ __forceinline__ u16 f2bf(float f){
  union { uint32_t u; float f2; } v; v.f2 = f;
  uint32_t x = v.u;
  return (u16)((x + 0x7FFFu + ((x >> 16) & 1u)) >> 16);  // RNE
}

// ---------------- one-time prep kernels ----------------

__global__ __launch_bounds__(256) void k_convert_x(const float4* __restrict__ X, ushort4* __restrict__ Xb, int n4){
  int i = blockIdx.x * blockDim.x + threadIdx.x;
  int stride = gridDim.x * blockDim.x;
  for (; i < n4; i += stride){
    float4 v = X[i];
    ushort4 o;
    o.x = f2bf(v.x); o.y = f2bf(v.y); o.z = f2bf(v.z); o.w = f2bf(v.w);
    Xb[i] = o;
  }
}

__global__ __launch_bounds__(256) void k_convert_wkv(const float* __restrict__ Wk, const float* __restrict__ Wv, u16* __restrict__ Wkv){
  int i = blockIdx.x * 256 + threadIdx.x;   // exactly 1024*512
  int n = i >> 9;
  Wkv[i] = f2bf(n < 512 ? Wk[i] : Wv[i - 262144]);
}

__global__ __launch_bounds__(256) void k_transpose_gates(const float* __restrict__ W_ih, const float* __restrict__ W_hh, float* __restrict__ Wt){
  int i = blockIdx.x * 256 + threadIdx.x;   // exactly 576*2048
  int k = i >> 11, n = i & 2047;
  Wt[i] = (k < 64) ? W_ih[n * 64 + k] : W_hh[n * 512 + (k - 64)];
}

__global__ __launch_bounds__(256) void k_transpose_wq(const float* __restrict__ Wq, float* __restrict__ Wqt){
  int i = blockIdx.x * 256 + threadIdx.x;   // exactly 512*512
  int k = i >> 9, n = i & 511;
  Wqt[i] = Wq[n * 512 + k];
}

__global__ __launch_bounds__(256) void k_precomb(const float* __restrict__ Wfc, const float* __restrict__ Wo,
                                                 const float* __restrict__ bo, const float* __restrict__ bfc,
                                                 float* __restrict__ Mt, float* __restrict__ bcomb){
  int i = blockIdx.x * 256 + threadIdx.x;
  if (i < 32768){
    int d = i >> 6, p = i & 63;
    float acc = 0.f;
    for (int j = 0; j < 512; j++) acc += Wfc[p * 512 + j] * Wo[j * 512 + d];
    Mt[i] = acc;                      // Mt[d*64+p] = sum_j Wfc[p][j]*Wo[j][d]
  } else if (i < 32832){
    int p = i - 32768;
    float acc = bfc[p];
    for (int j = 0; j < 512; j++) acc += Wfc[p * 512 + j] * bo[j];
    bcomb[p] = acc;
  }
}

__global__ __launch_bounds__(256) void k_init(const float* __restrict__ dec, const float* __restrict__ h0,
                                              const float* __restrict__ c0, float* __restrict__ xh0, float* __restrict__ cbuf){
  int i = blockIdx.x * 256 + threadIdx.x;   // exactly 128*576 + 128*512 = 139264
  if (i < 73728){
    int b = i / 576, col = i % 576;
    xh0[i] = (col < 64) ? dec[b * 64 + col] : h0[b * 512 + (col - 64)];
  } else {
    int j = i - 73728;
    cbuf[j] = c0[j];
  }
}

// ---------------- phase 1: K/V projection (bf16 MFMA GEMM) ----------------
// C[m][n] = sum_k Xb[m][k]*Wkv[n][k] + bias[n]; m=b*512+l, n<512 -> K head/hd, n>=512 -> V.
__global__ __launch_bounds__(256) void k_gemm_kv(const u16* __restrict__ Xb, const u16* __restrict__ Wkv,
                                                 const float* __restrict__ bk, const float* __restrict__ bv,
                                                 u16* __restrict__ Kb, u16* __restrict__ Vb){
  __shared__ __align__(16) u16 As[128 * 72];
  __shared__ __align__(16) u16 Bs[128 * 72];
  const int tid = threadIdx.x;
  const int lane = tid & 63, wid = tid >> 6;
  const int wm = wid >> 1, wn = wid & 1;      // 2x2 wave grid, 64x64 per wave
  const int m0 = blockIdx.x * 128, n0 = blockIdx.y * 128;

  f32x4 zero = {0.f, 0.f, 0.f, 0.f};
  f32x4 acc[4][4];
  #pragma unroll
  for (int i = 0; i < 4; i++)
    #pragma unroll
    for (int j = 0; j < 4; j++) acc[i][j] = zero;

  for (int kt = 0; kt < 512; kt += 64){
    #pragma unroll
    for (int s = 0; s < 4; s++){
      int slot = tid + 256 * s;               // 0..1023
      int r = slot >> 3, cg = (slot & 7) * 8;
      *(uint4*)&As[r * 72 + cg] = *(const uint4*)&Xb[(size_t)(m0 + r) * 512 + kt + cg];
      *(uint4*)&Bs[r * 72 + cg] = *(const uint4*)&Wkv[(size_t)(n0 + r) * 512 + kt + cg];
    }
    __syncthreads();
    #pragma unroll
    for (int ks = 0; ks < 2; ks++){
      bf16x8 af[4], bfr[4];
      int col = ks * 32 + (lane >> 4) * 8;
      int ra = wm * 64 + (lane & 15);
      int rb = wn * 64 + (lane & 15);
      #pragma unroll
      for (int i = 0; i < 4; i++) af[i]  = *(const bf16x8*)&As[(ra + i * 16) * 72 + col];
      #pragma unroll
      for (int j = 0; j < 4; j++) bfr[j] = *(const bf16x8*)&Bs[(rb + j * 16) * 72 + col];
      #pragma unroll
      for (int i = 0; i < 4; i++)
        #pragma unroll
        for (int j = 0; j < 4; j++)
          acc[i][j] = __builtin_amdgcn_mfma_f32_16x16x32_bf16(af[i], bfr[j], acc[i][j], 0, 0, 0);
    }
    __syncthreads();
  }

  #pragma unroll
  for (int j = 0; j < 4; j++){
    int n = n0 + wn * 64 + j * 16 + (lane & 15);
    float bias = (n < 512) ? bk[n] : bv[n - 512];
    u16* dst = (n < 512) ? Kb : Vb;
    int nh = (n >> 6) & 7, hd = n & 63;
    #pragma unroll
    for (int i = 0; i < 4; i++){
      #pragma unroll
      for (int r = 0; r < 4; r++){
        int m = m0 + wm * 64 + i * 16 + (lane >> 4) * 4 + r;
        int b = m >> 9, l = m & 511;
        float val = acc[i][j][r] + bias;
        dst[((size_t)((b * 8 + nh) * 512 + l)) * 64 + hd] = f2bf(val);
      }
    }
  }
}

// ---------------- per-step kernels (fp32) ----------------

// gates = x@W_ih.T + h@W_hh.T + b_ih + b_hh (k-major Wt), fused LSTM update.
// tile: 8 b x 32 j per block; thread computes all 4 gates for one (b,j).
__global__ __launch_bounds__(256) void k_gates_lstm(const float* __restrict__ xh_cur, float* __restrict__ xh_next,
                                                    float* __restrict__ cbuf, const float* __restrict__ Wt,
                                                    const float* __restrict__ b_ih, const float* __restrict__ b_hh){
  __shared__ float xs[8][KCAT];
  const int tid = threadIdx.x;
  const int bl = tid >> 5, jl = tid & 31;
  const int b0 = blockIdx.x * 8;
  const int j = blockIdx.y * 32 + jl;
  for (int r = 0; r < 8; r++)
    for (int c = tid; c < KCAT; c += 256)
      xs[r][c] = xh_cur[(b0 + r) * KCAT + c];
  __syncthreads();
  float a0 = b_ih[j] + b_hh[j];
  float a1 = b_ih[512 + j] + b_hh[512 + j];
  float a2 = b_ih[1024 + j] + b_hh[1024 + j];
  float a3 = b_ih[1536 + j] + b_hh[1536 + j];
  const float* Wc = Wt + j;
  #pragma unroll 4
  for (int k = 0; k < KCAT; k++){
    float x = xs[bl][k];
    const float* w = Wc + (size_t)k * 2048;
    a0 += x * w[0];
    a1 += x * w[512];
    a2 += x * w[1024];
    a3 += x * w[1536];
  }
  int b = b0 + bl;
  float c_old = cbuf[b * 512 + j];
  float ig = 1.f / (1.f + __expf(-a0));
  float fg = 1.f / (1.f + __expf(-a1));
  float e2 = __expf(2.f * a2);
  float gg = 1.f - 2.f / (e2 + 1.f);          // tanh(a2), saturation-safe
  float og = 1.f / (1.f + __expf(-a3));
  float cn = fg * c_old + ig * gg;
  float ec = __expf(2.f * cn);
  float th = 1.f - 2.f / (ec + 1.f);          // tanh(cn)
  cbuf[b * 512 + j] = cn;
  xh_next[b * KCAT + 64 + j] = og * th;
}

// q = h@Wq.T + bq (k-major Wqt). tile 8b x 32n.
__global__ __launch_bounds__(256) void k_q(const float* __restrict__ xh, const float* __restrict__ Wqt,
                                           const float* __restrict__ bq, float* __restrict__ qbuf){
  __shared__ float hs[8][512];
  const int tid = threadIdx.x;
  const int bl = tid >> 5, nl = tid & 31;
  const int b0 = blockIdx.x * 8;
  const int n = blockIdx.y * 32 + nl;
  for (int r = 0; r < 8; r++)
    for (int c = tid; c < 512; c += 256)
      hs[r][c] = xh[(b0 + r) * KCAT + 64 + c];
  __syncthreads();
  float acc = bq[n];
  #pragma unroll 4
  for (int k = 0; k < 512; k++)
    acc += hs[bl][k] * Wqt[(size_t)k * 512 + n];
  qbuf[(b0 + bl) * 512 + n] = acc;
}

// attention: one block per (b,nh). scores -> softmax -> attn map write -> ctx.
__global__ __launch_bounds__(256) void k_attn(const float* __restrict__ qbuf, const u16* __restrict__ Kb,
                                              const u16* __restrict__ Vb, float* __restrict__ attn_out,
                                              float* __restrict__ ctx, int t){
  const int bx = blockIdx.x;                  // b*8+nh
  const int b = bx >> 3, nh = bx & 7;
  const int tid = threadIdx.x;
  const int lane = tid & 63, wid = tid >> 6;
  __shared__ float qs[64];
  __shared__ float sc[512];
  __shared__ float red[16];
  __shared__ float ctxp[4][64];
  if (tid < 64) qs[tid] = qbuf[b * 512 + nh * 64 + tid];
  __syncthreads();
  const u16* Kp = Kb + (size_t)bx * (512 * 64);
  float s[2];
  #pragma unroll
  for (int ii = 0; ii < 2; ii++){
    int l = tid + ii * 256;
    const u16* kr = Kp + l * 64;
    float acc = 0.f;
    #pragma unroll
    for (int g = 0; g < 8; g++){
      uint4 v = *(const uint4*)(kr + g * 8);
      const float* q8 = qs + g * 8;
      acc += bfbits2f(v.x << 16)          * q8[0];
      acc += bfbits2f(v.x & 0xffff0000u)  * q8[1];
      acc += bfbits2f(v.y << 16)          * q8[2];
      acc += bfbits2f(v.y & 0xffff0000u)  * q8[3];
      acc += bfbits2f(v.z << 16)          * q8[4];
      acc += bfbits2f(v.z & 0xffff0000u)  * q8[5];
      acc += bfbits2f(v.w << 16)          * q8[6];
      acc += bfbits2f(v.w & 0xffff0000u)  * q8[7];
    }
    s[ii] = acc * 0.125f;
  }
  float m = fmaxf(s[0], s[1]);
  for (int off = 32; off > 0; off >>= 1) m = fmaxf(m, __shfl_down(m, off));
  if (lane == 0) red[wid] = m;
  __syncthreads();
  if (tid == 0) red[8] = fmaxf(fmaxf(red[0], red[1]), fmaxf(red[2], red[3]));
  __syncthreads();
  float mx = red[8];
  float e0 = __expf(s[0] - mx), e1 = __expf(s[1] - mx);
  float ps = e0 + e1;
  for (int off = 32; off > 0; off >>= 1) ps += __shfl_down(ps, off);
  if (lane == 0) red[4 + wid] = ps;
  __syncthreads();
  if (tid == 0) red[9] = 1.f / (red[4] + red[5] + red[6] + red[7]);
  __syncthreads();
  float inv = red[9];
  float a0 = e0 * inv, a1 = e1 * inv;
  sc[tid] = a0; sc[tid + 256] = a1;
  float* aout = attn_out + ((size_t)bx * HOR_ + t) * 512;
  aout[tid] = a0; aout[tid + 256] = a1;
  __syncthreads();
  const u16* Vp = Vb + (size_t)bx * (512 * 64);
  const int d = tid & 63, part = tid >> 6;
  float acc = 0.f;
  const u16* vp = Vp + part * 128 * 64 + d;
  const float* scp = sc + part * 128;
  for (int l = 0; l < 128; l++)
    acc += scp[l] * bf2f(vp[l * 64]);
  ctxp[part][d] = acc;
  __syncthreads();
  if (tid < 64)
    ctx[b * 512 + nh * 64 + tid] = ctxp[0][tid] + ctxp[1][tid] + ctxp[2][tid] + ctxp[3][tid];
}

// pred = ctx @ (Wfc@Wo).T + (Wfc@bo + bfc); writes output slice and x for next step.
__global__ __launch_bounds__(256) void k_pred(const float* __restrict__ ctx, const float* __restrict__ Mt,
                                              const float* __restrict__ bcomb, float* __restrict__ outp,
                                              float* __restrict__ xh_next, int t){
  __shared__ float cs[4][512];
  const int tid = threadIdx.x;
  const int p = tid & 63, bl = tid >> 6;
  const int b0 = blockIdx.x * 4;
  for (int i = tid; i < 4 * 512; i += 256){
    int r = i >> 9, c = i & 511;
    cs[r][c] = ctx[(b0 + r) * 512 + c];
  }
  __syncthreads();
  float acc = bcomb[p];
  #pragma unroll 4
  for (int dd = 0; dd < 512; dd++)
    acc += cs[bl][dd] * Mt[dd * 64 + p];
  int b = b0 + bl;
  outp[(size_t)b * (HOR_ * OUT_) + t * OUT_ + p] = acc;
  xh_next[b * KCAT + p] = acc;
}

// ---------------- host launcher ----------------

extern "C" void kernel_launch(void* const* d_in, const int* in_sizes, int n_in,
                              void* d_out, int out_size, void* d_ws, size_t ws_size,
                              hipStream_t stream){
  const float* enc  = (const float*)d_in[0];
  const float* h0   = (const float*)d_in[1];
  const float* c0   = (const float*)d_in[2];
  const float* dec  = (const float*)d_in[3];
  const float* W_ih = (const float*)d_in[4];
  const float* W_hh = (const float*)d_in[5];
  const float* b_ih = (const float*)d_in[6];
  const float* b_hh = (const float*)d_in[7];
  const float* Wq   = (const float*)d_in[8];
  const float* bq   = (const float*)d_in[9];
  const float* Wk   = (const float*)d_in[10];
  const float* bk   = (const float*)d_in[11];
  const float* Wv   = (const float*)d_in[12];
  const float* bv   = (const float*)d_in[13];
  const float* Wo   = (const float*)d_in[14];
  const float* bo   = (const float*)d_in[15];
  const float* Wfc  = (const float*)d_in[16];
  const float* bfc  = (const float*)d_in[17];
  float* out = (float*)d_out;

  char* ws = (char*)d_ws;
  size_t off = 0;
  auto alloc = [&](size_t bytes){ void* p = ws + off; off += (bytes + 255) & ~(size_t)255; return p; };
  u16*   Xb    = (u16*)  alloc((size_t)B_ * L_ * H_ * 2);
  u16*   Kb    = (u16*)  alloc((size_t)B_ * NH_ * L_ * HD_ * 2);
  u16*   Vb    = (u16*)  alloc((size_t)B_ * NH_ * L_ * HD_ * 2);
  u16*   Wkv   = (u16*)  alloc((size_t)1024 * 512 * 2);
  float* Wt    = (float*)alloc((size_t)KCAT * G4H * 4);
  float* Wqt   = (float*)alloc((size_t)512 * 512 * 4);
  float* Mt    = (float*)alloc((size_t)512 * 64 * 4);
  float* bcomb = (float*)alloc(64 * 4);
  float* xh0   = (float*)alloc((size_t)B_ * KCAT * 4);
  float* xh1   = (float*)alloc((size_t)B_ * KCAT * 4);
  float* cbuf  = (float*)alloc((size_t)B_ * H_ * 4);
  float* qbuf  = (float*)alloc((size_t)B_ * H_ * 4);
  float* ctx   = (float*)alloc((size_t)B_ * H_ * 4);
  if (off > ws_size){
    fprintf(stderr, "WORKSPACE TOO SMALL: need %zu, have %zu\n", off, ws_size);
  }

  float* out_pred = out;                                 // (B, HOR, OUT)
  float* out_attn = out + (size_t)B_ * HOR_ * OUT_;      // (B, NH, HOR, L)

  k_convert_x<<<4096, 256, 0, stream>>>((const float4*)enc, (ushort4*)Xb, (B_ * L_ * H_) / 4);
  k_convert_wkv<<<2048, 256, 0, stream>>>(Wk, Wv, Wkv);
  k_transpose_gates<<<4608, 256, 0, stream>>>(W_ih, W_hh, Wt);
  k_transpose_wq<<<1024, 256, 0, stream>>>(Wq, Wqt);
  k_precomb<<<129, 256, 0, stream>>>(Wfc, Wo, bo, bfc, Mt, bcomb);
  k_init<<<544, 256, 0, stream>>>(dec, h0, c0, xh0, cbuf);
  k_gemm_kv<<<dim3(512, 8), 256, 0, stream>>>(Xb, Wkv, bk, bv, Kb, Vb);

  float* xh[2] = {xh0, xh1};
  for (int t = 0; t < HOR_; t++){
    float* cur = xh[t & 1];
    float* nxt = xh[(t + 1) & 1];
    k_gates_lstm<<<dim3(16, 16), 256, 0, stream>>>(cur, nxt, cbuf, Wt, b_ih, b_hh);
    k_q<<<dim3(16, 16), 256, 0, stream>>>(nxt, Wqt, bq, qbuf);
    k_attn<<<1024, 256, 0, stream>>>(qbuf, Kb, Vb, out_attn, ctx, t);
    k_pred<<<32, 256, 0, stream>>>(ctx, Mt, bcomb, out_pred, nxt, t);
  }
}

// Round 2
// 2173.605 us; speedup vs baseline: 2.1186x; 2.1186x over previous
//
#include <hip/hip_runtime.h>
#include <cstdio>
#include <cstdint>

#define B_   128
#define L_   512
#define H_   512
#define IN_  64
#define OUT_ 64
#define NH_  8
#define HD_  64
#define HOR_ 24
#define KCAT 576   // IN_ + H_
#define G4H  2048  // 4*H_

typedef unsigned short u16;
typedef __attribute__((ext_vector_type(8))) __bf16 bf16x8;
typedef __attribute__((ext_vector_type(4))) float f32x4;

__device__ __forceinline__ float bfbits2f(uint32_t hi){ union { uint32_t u; float f; } v; v.u = hi; return v.f; }
__device__ __forceinline__ float bf2f(u16 u){ union { uint32_t u; float f; } v; v.u = ((uint32_t)u) << 16; return v.f; }
__device__ __forceinline__ u16 f2bf(float f){
  union { uint32_t u; float f2; } v; v.f2 = f;
  uint32_t x = v.u;
  return (u16)((x + 0x7FFFu + ((x >> 16) & 1u)) >> 16);  // RNE
}

// ---------------- one-time prep ----------------

__global__ __launch_bounds__(256) void k_convert_x(const float4* __restrict__ X, ushort4* __restrict__ Xb, int n4){
  int i = blockIdx.x * blockDim.x + threadIdx.x;
  int stride = gridDim.x * blockDim.x;
  for (; i < n4; i += stride){
    float4 v = X[i];
    ushort4 o;
    o.x = f2bf(v.x); o.y = f2bf(v.y); o.z = f2bf(v.z); o.w = f2bf(v.w);
    Xb[i] = o;
  }
}

// fused small prep: block ranges
//  [0,129)      Mt (heavy: Wfc@Wo) + bcomb
//  [129,2177)   Wkv bf16 convert
//  [2177,6785)  Wt4 interleaved gate weights
//  [6785,7809)  Wqt transpose
//  [7809,7817)  bias4
//  [7817,8361)  xh0 / cbuf init
__global__ __launch_bounds__(256) void k_prep(const float* __restrict__ Wk, const float* __restrict__ Wv,
                                              const float* __restrict__ W_ih, const float* __restrict__ W_hh,
                                              const float* __restrict__ b_ih, const float* __restrict__ b_hh,
                                              const float* __restrict__ Wq, const float* __restrict__ Wfc,
                                              const float* __restrict__ Wo, const float* __restrict__ bo,
                                              const float* __restrict__ bfc, const float* __restrict__ dec,
                                              const float* __restrict__ h0, const float* __restrict__ c0,
                                              u16* __restrict__ Wkv, float* __restrict__ Wt4,
                                              float* __restrict__ Wqt, float* __restrict__ bias4,
                                              float* __restrict__ Mt, float* __restrict__ bcomb,
                                              float* __restrict__ xh0, float* __restrict__ cbuf){
  const int bid = blockIdx.x, tid = threadIdx.x;
  if (bid < 129){
    int i = bid * 256 + tid;
    if (i < 32768){
      int p = i >> 9, d = i & 511;
      float acc = 0.f;
      #pragma unroll 4
      for (int j = 0; j < 512; j++) acc += Wfc[p * 512 + j] * Wo[j * 512 + d];
      Mt[d * 64 + p] = acc;
    } else if (i < 32832){
      int p = i - 32768;
      float acc = bfc[p];
      for (int j = 0; j < 512; j++) acc += Wfc[p * 512 + j] * bo[j];
      bcomb[p] = acc;
    }
  } else if (bid < 2177){
    int i = (bid - 129) * 256 + tid;           // 1024*512
    int n = i >> 9;
    Wkv[i] = f2bf(n < 512 ? Wk[i] : Wv[i - 262144]);
  } else if (bid < 6785){
    int i = (bid - 2177) * 256 + tid;          // 576*2048
    int k = i >> 11, rem = i & 2047;
    int j = rem >> 2, g = rem & 3;
    int row = g * 512 + j;
    Wt4[i] = (k < 64) ? W_ih[row * 64 + k] : W_hh[row * 512 + (k - 64)];
  } else if (bid < 7809){
    int i = (bid - 6785) * 256 + tid;          // 512*512
    int k = i >> 9, n = i & 511;
    Wqt[i] = Wq[n * 512 + k];
  } else if (bid < 7817){
    int i = (bid - 7809) * 256 + tid;          // 2048
    int j = i >> 2, g = i & 3;
    bias4[i] = b_ih[g * 512 + j] + b_hh[g * 512 + j];
  } else {
    int i = (bid - 7817) * 256 + tid;          // 73728 + 65536
    if (i < 73728){
      int b = i / 576, col = i % 576;
      xh0[i] = (col < 64) ? dec[b * 64 + col] : h0[b * 512 + (col - 64)];
    } else {
      int j = i - 73728;
      cbuf[j] = c0[j];
    }
  }
}

// ---------------- phase 1: K/V projection (bf16 MFMA GEMM) ----------------
// grid (8 n-tiles, 512 m-tiles): consecutive blocks share the A (Xb) tile.
// LDS: unpadded stride-64 rows with XOR group swizzle -> conflict-free b128.
__global__ __launch_bounds__(256) void k_gemm_kv(const u16* __restrict__ Xb, const u16* __restrict__ Wkv,
                                                 const float* __restrict__ bk, const float* __restrict__ bv,
                                                 u16* __restrict__ Kb, u16* __restrict__ Vb){
  __shared__ __align__(16) u16 As[128 * 64];
  __shared__ __align__(16) u16 Bs[128 * 64];
  const int tid = threadIdx.x;
  const int lane = tid & 63, wid = tid >> 6;
  const int wm = wid >> 1, wn = wid & 1;
  const int n0 = blockIdx.x * 128, m0 = blockIdx.y * 128;

  f32x4 zero = {0.f, 0.f, 0.f, 0.f};
  f32x4 acc[4][4];
  #pragma unroll
  for (int i = 0; i < 4; i++)
    #pragma unroll
    for (int j = 0; j < 4; j++) acc[i][j] = zero;

  for (int kt = 0; kt < 512; kt += 64){
    #pragma unroll
    for (int s = 0; s < 4; s++){
      int slot = tid + 256 * s;                // 0..1023
      int r = slot >> 3, cg = slot & 7;
      int sw = (cg ^ (r & 7)) << 3;
      *(uint4*)&As[r * 64 + sw] = *(const uint4*)&Xb[(size_t)(m0 + r) * 512 + kt + cg * 8];
      *(uint4*)&Bs[r * 64 + sw] = *(const uint4*)&Wkv[(size_t)(n0 + r) * 512 + kt + cg * 8];
    }
    __syncthreads();
    #pragma unroll
    for (int ks = 0; ks < 2; ks++){
      bf16x8 af[4], bfr[4];
      int g = ks * 4 + (lane >> 4);
      int ra = wm * 64 + (lane & 15);
      int rb = wn * 64 + (lane & 15);
      #pragma unroll
      for (int i = 0; i < 4; i++){
        int r = ra + i * 16;
        af[i] = *(const bf16x8*)&As[r * 64 + ((g ^ (r & 7)) << 3)];
      }
      #pragma unroll
      for (int j = 0; j < 4; j++){
        int r = rb + j * 16;
        bfr[j] = *(const bf16x8*)&Bs[r * 64 + ((g ^ (r & 7)) << 3)];
      }
      #pragma unroll
      for (int i = 0; i < 4; i++)
        #pragma unroll
        for (int j = 0; j < 4; j++)
          acc[i][j] = __builtin_amdgcn_mfma_f32_16x16x32_bf16(af[i], bfr[j], acc[i][j], 0, 0, 0);
    }
    __syncthreads();
  }

  #pragma unroll
  for (int j = 0; j < 4; j++){
    int n = n0 + wn * 64 + j * 16 + (lane & 15);
    float bias = (n < 512) ? bk[n] : bv[n - 512];
    u16* dst = (n < 512) ? Kb : Vb;
    int nh = (n >> 6) & 7, hd = n & 63;
    #pragma unroll
    for (int i = 0; i < 4; i++){
      #pragma unroll
      for (int r = 0; r < 4; r++){
        int m = m0 + wm * 64 + i * 16 + (lane >> 4) * 4 + r;
        int b = m >> 9, l = m & 511;
        float val = acc[i][j][r] + bias;
        dst[((size_t)((b * 8 + nh) * 512 + l)) * 64 + hd] = f2bf(val);
      }
    }
  }
}

// ---------------- per-step kernels ----------------

// gates GEMM (128x2048xK576, fp32) + LSTM. Wt4 interleaved: [k][j][4 gates].
// 1024 threads: 4-way k-split (144 k each), tile 8b x 32j, grid (16,16).
__global__ __launch_bounds__(1024) void k_gates_lstm(const float* __restrict__ xh_cur, float* __restrict__ xh_next,
                                                     float* __restrict__ cbuf, const float4* __restrict__ Wt4,
                                                     const float4* __restrict__ bias4){
  __shared__ float xs[8][KCAT];
  __shared__ float4 psum[3][8][32];
  const int tid = threadIdx.x;
  const int quarter = tid >> 8;
  const int tq = tid & 255;
  const int r = tq >> 5, jl = tq & 31;
  const int b0 = blockIdx.x * 8;
  const int j = blockIdx.y * 32 + jl;

  for (int i = tid; i < 8 * KCAT; i += 1024){
    int rr = i / KCAT, c = i - rr * KCAT;
    xs[rr][c] = xh_cur[(b0 + rr) * KCAT + c];
  }
  __syncthreads();

  float4 a = {0.f, 0.f, 0.f, 0.f};
  const float4* W = Wt4 + (size_t)(quarter * 144) * 512 + j;
  const float* x = &xs[r][quarter * 144];
  #pragma unroll 8
  for (int k = 0; k < 144; k++){
    float xv = x[k];
    float4 w = W[(size_t)k * 512];
    a.x += xv * w.x; a.y += xv * w.y; a.z += xv * w.z; a.w += xv * w.w;
  }
  if (quarter > 0) psum[quarter - 1][r][jl] = a;
  __syncthreads();
  if (quarter == 0){
    float4 p0 = psum[0][r][jl], p1 = psum[1][r][jl], p2 = psum[2][r][jl];
    float4 bs = bias4[j];
    float ai = a.x + p0.x + p1.x + p2.x + bs.x;
    float af = a.y + p0.y + p1.y + p2.y + bs.y;
    float ag = a.z + p0.z + p1.z + p2.z + bs.z;
    float ao = a.w + p0.w + p1.w + p2.w + bs.w;
    int b = b0 + r;
    float c_old = cbuf[b * 512 + j];
    float ig = 1.f / (1.f + __expf(-ai));
    float fg = 1.f / (1.f + __expf(-af));
    float e2 = __expf(2.f * ag);
    float gg = 1.f - 2.f / (e2 + 1.f);
    float og = 1.f / (1.f + __expf(-ao));
    float cn = fg * c_old + ig * gg;
    float ec = __expf(2.f * cn);
    float th = 1.f - 2.f / (ec + 1.f);
    cbuf[b * 512 + j] = cn;
    xh_next[b * KCAT + 64 + j] = og * th;
  }
}

// fused q-projection + attention. one block per (b,nh).
__global__ __launch_bounds__(256) void k_attn(const float* __restrict__ xh, const float* __restrict__ Wqt,
                                              const float* __restrict__ bq, const u16* __restrict__ Kb,
                                              const u16* __restrict__ Vb, float* __restrict__ attn_out,
                                              float* __restrict__ ctx, int t){
  const int bx = blockIdx.x;
  const int b = bx >> 3, nh = bx & 7;
  const int tid = threadIdx.x;
  const int lane = tid & 63, wid = tid >> 6;
  __shared__ float hs[512];
  __shared__ float qred[4][64];
  __shared__ float qs[64];
  __shared__ float sc[512];
  __shared__ float red[16];
  __shared__ float ctxp[4][64];

  hs[tid] = xh[b * KCAT + 64 + tid];
  hs[tid + 256] = xh[b * KCAT + 64 + tid + 256];
  __syncthreads();

  // q[d] = bq + h . Wq[nh*64+d], k-split 4 ways; fold 1/sqrt(HD) into q.
  {
    const int d = tid & 63, part = tid >> 6;
    float qa = 0.f;
    const float* wp = Wqt + (size_t)(part * 128) * 512 + nh * 64 + d;
    const float* hp = &hs[part * 128];
    #pragma unroll 8
    for (int k = 0; k < 128; k++)
      qa += hp[k] * wp[(size_t)k * 512];
    qred[part][d] = qa;
  }
  __syncthreads();
  if (tid < 64)
    qs[tid] = (qred[0][tid] + qred[1][tid] + qred[2][tid] + qred[3][tid] + bq[nh * 64 + tid]) * 0.125f;
  __syncthreads();

  const u16* Kp = Kb + (size_t)bx * (512 * 64);
  float s[2];
  #pragma unroll
  for (int ii = 0; ii < 2; ii++){
    int l = tid + ii * 256;
    const u16* kr = Kp + l * 64;
    float acc = 0.f;
    #pragma unroll
    for (int g = 0; g < 8; g++){
      uint4 v = *(const uint4*)(kr + g * 8);
      const float* q8 = qs + g * 8;
      acc += bfbits2f(v.x << 16)          * q8[0];
      acc += bfbits2f(v.x & 0xffff0000u)  * q8[1];
      acc += bfbits2f(v.y << 16)          * q8[2];
      acc += bfbits2f(v.y & 0xffff0000u)  * q8[3];
      acc += bfbits2f(v.z << 16)          * q8[4];
      acc += bfbits2f(v.z & 0xffff0000u)  * q8[5];
      acc += bfbits2f(v.w << 16)          * q8[6];
      acc += bfbits2f(v.w & 0xffff0000u)  * q8[7];
    }
    s[ii] = acc;
  }
  float m = fmaxf(s[0], s[1]);
  for (int off = 32; off > 0; off >>= 1) m = fmaxf(m, __shfl_down(m, off));
  if (lane == 0) red[wid] = m;
  __syncthreads();
  if (tid == 0) red[8] = fmaxf(fmaxf(red[0], red[1]), fmaxf(red[2], red[3]));
  __syncthreads();
  float mx = red[8];
  float e0 = __expf(s[0] - mx), e1 = __expf(s[1] - mx);
  float ps = e0 + e1;
  for (int off = 32; off > 0; off >>= 1) ps += __shfl_down(ps, off);
  if (lane == 0) red[4 + wid] = ps;
  __syncthreads();
  if (tid == 0) red[9] = 1.f / (red[4] + red[5] + red[6] + red[7]);
  __syncthreads();
  float inv = red[9];
  float a0 = e0 * inv, a1 = e1 * inv;
  sc[tid] = a0; sc[tid + 256] = a1;
  float* aout = attn_out + ((size_t)bx * HOR_ + t) * 512;
  aout[tid] = a0; aout[tid + 256] = a1;
  __syncthreads();

  // ctx: part=wave covers 128 l; lane = (lh, dg): d pair, 2 rows/inst, uint loads.
  const u16* Vp = Vb + (size_t)bx * (512 * 64);
  const int part = wid;
  const int dg = lane & 31, lh = lane >> 5;
  const int d = dg * 2;
  float c0a = 0.f, c1a = 0.f;
  const u16* vp = Vp + (size_t)(part * 128 + lh) * 64 + d;
  #pragma unroll 8
  for (int i = 0; i < 64; i++){
    int l = part * 128 + i * 2 + lh;
    uint32_t v = *(const uint32_t*)(vp + (size_t)i * 128);
    float w = sc[l];
    c0a += w * bfbits2f(v << 16);
    c1a += w * bfbits2f(v & 0xffff0000u);
  }
  c0a += __shfl_xor(c0a, 32);
  c1a += __shfl_xor(c1a, 32);
  if (lh == 0){ ctxp[part][d] = c0a; ctxp[part][d + 1] = c1a; }
  __syncthreads();
  if (tid < 64)
    ctx[b * 512 + nh * 64 + tid] = ctxp[0][tid] + ctxp[1][tid] + ctxp[2][tid] + ctxp[3][tid];
}

// pred = ctx @ Mt + bcomb; one block per b, k-split 4.
__global__ __launch_bounds__(256) void k_pred(const float* __restrict__ ctx, const float* __restrict__ Mt,
                                              const float* __restrict__ bcomb, float* __restrict__ outp,
                                              float* __restrict__ xh_next, int t){
  __shared__ float cs[512];
  __shared__ float pr[4][64];
  const int tid = threadIdx.x;
  const int b = blockIdx.x;
  cs[tid] = ctx[b * 512 + tid];
  cs[tid + 256] = ctx[b * 512 + tid + 256];
  __syncthreads();
  const int p = tid & 63, part = tid >> 6;
  float acc = 0.f;
  const float* mp = Mt + (size_t)(part * 128) * 64 + p;
  const float* cp = &cs[part * 128];
  #pragma unroll 8
  for (int i = 0; i < 128; i++)
    acc += cp[i] * mp[(size_t)i * 64];
  pr[part][p] = acc;
  __syncthreads();
  if (tid < 64){
    float v = pr[0][tid] + pr[1][tid] + pr[2][tid] + pr[3][tid] + bcomb[tid];
    outp[(size_t)b * (HOR_ * OUT_) + t * OUT_ + tid] = v;
    xh_next[b * KCAT + tid] = v;
  }
}

// ---------------- host launcher ----------------

extern "C" void kernel_launch(void* const* d_in, const int* in_sizes, int n_in,
                              void* d_out, int out_size, void* d_ws, size_t ws_size,
                              hipStream_t stream){
  const float* enc  = (const float*)d_in[0];
  const float* h0   = (const float*)d_in[1];
  const float* c0   = (const float*)d_in[2];
  const float* dec  = (const float*)d_in[3];
  const float* W_ih = (const float*)d_in[4];
  const float* W_hh = (const float*)d_in[5];
  const float* b_ih = (const float*)d_in[6];
  const float* b_hh = (const float*)d_in[7];
  const float* Wq   = (const float*)d_in[8];
  const float* bq   = (const float*)d_in[9];
  const float* Wk   = (const float*)d_in[10];
  const float* bk   = (const float*)d_in[11];
  const float* Wv   = (const float*)d_in[12];
  const float* bv   = (const float*)d_in[13];
  const float* Wo   = (const float*)d_in[14];
  const float* bo   = (const float*)d_in[15];
  const float* Wfc  = (const float*)d_in[16];
  const float* bfc  = (const float*)d_in[17];
  float* out = (float*)d_out;

  char* ws = (char*)d_ws;
  size_t off = 0;
  auto alloc = [&](size_t bytes){ void* p = ws + off; off += (bytes + 255) & ~(size_t)255; return p; };
  u16*   Xb    = (u16*)  alloc((size_t)B_ * L_ * H_ * 2);
  u16*   Kb    = (u16*)  alloc((size_t)B_ * NH_ * L_ * HD_ * 2);
  u16*   Vb    = (u16*)  alloc((size_t)B_ * NH_ * L_ * HD_ * 2);
  u16*   Wkv   = (u16*)  alloc((size_t)1024 * 512 * 2);
  float* Wt4   = (float*)alloc((size_t)KCAT * G4H * 4);
  float* Wqt   = (float*)alloc((size_t)512 * 512 * 4);
  float* Mt    = (float*)alloc((size_t)512 * 64 * 4);
  float* bcomb = (float*)alloc(64 * 4);
  float* bias4 = (float*)alloc((size_t)G4H * 4);
  float* xh0   = (float*)alloc((size_t)B_ * KCAT * 4);
  float* xh1   = (float*)alloc((size_t)B_ * KCAT * 4);
  float* cbuf  = (float*)alloc((size_t)B_ * H_ * 4);
  float* ctx   = (float*)alloc((size_t)B_ * H_ * 4);
  if (off > ws_size){
    fprintf(stderr, "WORKSPACE TOO SMALL: need %zu, have %zu\n", off, ws_size);
  }

  float* out_pred = out;                                 // (B, HOR, OUT)
  float* out_attn = out + (size_t)B_ * HOR_ * OUT_;      // (B, NH, HOR, L)

  k_convert_x<<<4096, 256, 0, stream>>>((const float4*)enc, (ushort4*)Xb, (B_ * L_ * H_) / 4);
  k_prep<<<8361, 256, 0, stream>>>(Wk, Wv, W_ih, W_hh, b_ih, b_hh, Wq, Wfc, Wo, bo, bfc,
                                   dec, h0, c0, Wkv, Wt4, Wqt, bias4, Mt, bcomb, xh0, cbuf);
  k_gemm_kv<<<dim3(8, 512), 256, 0, stream>>>(Xb, Wkv, bk, bv, Kb, Vb);

  float* xh[2] = {xh0, xh1};
  for (int t = 0; t < HOR_; t++){
    float* cur = xh[t & 1];
    float* nxt = xh[(t + 1) & 1];
    k_gates_lstm<<<dim3(16, 16), 1024, 0, stream>>>(cur, nxt, cbuf, (const float4*)Wt4, (const float4*)bias4);
    k_attn<<<1024, 256, 0, stream>>>(nxt, Wqt, bq, Kb, Vb, out_attn, ctx, t);
    k_pred<<<128, 256, 0, stream>>>(ctx, Mt, bcomb, out_pred, nxt, t);
  }
}